// Round 7
// baseline (608.620 us; speedup 1.0000x reference)
//
#include <hip/hip_runtime.h>
#include <hip/hip_bf16.h>
#include <stdint.h>

#define NUM_EXPERTS 32
#define HIDDEN 2048
#define INTER 2816
#define HALFI 1408
#define TOKENS 1024
#define TOPK 8
#define TA (TOKENS*TOPK)
#define CAP 512
#define BK 32

typedef float f32x4 __attribute__((ext_vector_type(4)));
typedef __bf16 bf16x8 __attribute__((ext_vector_type(8)));
typedef unsigned int u32;
typedef __attribute__((address_space(3))) u32 lds_u32;
typedef __attribute__((address_space(1))) const u32 glb_u32;

__device__ __forceinline__ void gload16(const void* g, void* l) {
  // async global->LDS DMA, 16B/lane; per-lane GLOBAL addr ok, LDS dest = wave base + lane*16
  __builtin_amdgcn_global_load_lds((glb_u32*)g, (lds_u32*)l, 16, 0, 0);
}
__device__ __forceinline__ uint32_t pk2(float a, float b) {
  union { __bf16 h[2]; uint32_t u; } c;
  c.h[0] = (__bf16)a; c.h[1] = (__bf16)b; return c.u;
}
__device__ __forceinline__ uint16_t bf16b(float a) {
  union { __bf16 h; uint16_t u; } c; c.h = (__bf16)a; return c.u;
}
__device__ __forceinline__ bf16x8 cvt8(f32x4 lo, f32x4 hi) {
  bf16x8 r;
  r[0] = (__bf16)lo.x; r[1] = (__bf16)lo.y; r[2] = (__bf16)lo.z; r[3] = (__bf16)lo.w;
  r[4] = (__bf16)hi.x; r[5] = (__bf16)hi.y; r[6] = (__bf16)hi.z; r[7] = (__bf16)hi.w;
  return r;
}

// ---------------- routing ----------------
__global__ void route_count(const int* __restrict__ tkidx, int* __restrict__ offs) {
  __shared__ int cnt[NUM_EXPERTS];
  int tid = threadIdx.x;
  if (tid < NUM_EXPERTS) cnt[tid] = 0;
  __syncthreads();
  for (int i = tid; i < TA; i += 256) atomicAdd(&cnt[tkidx[i]], 1);
  __syncthreads();
  if (tid == 0) {
    int acc = 0;
    for (int e = 0; e < NUM_EXPERTS; ++e) { offs[e] = acc; acc += cnt[e]; }
    offs[NUM_EXPERTS] = acc;
  }
}

__global__ void route_build(const int* __restrict__ tkidx, const float* __restrict__ tkw,
                            const int* __restrict__ offs,
                            int* __restrict__ tok_of_row, float* __restrict__ w_of_row) {
  int e = blockIdx.x;
  int lane = threadIdx.x;
  int base = offs[e];
  int run = 0;
  for (int c0 = 0; c0 < TA; c0 += 64) {
    int i = c0 + lane;
    bool p = (tkidx[i] == e);
    unsigned long long m = __ballot(p);
    if (p) {
      int rank = run + __popcll(m & ((1ull << lane) - 1ull));
      if (rank < CAP) {
        tok_of_row[base + rank] = i >> 3;   // TOPK = 8
        w_of_row[base + rank]   = tkw[i];
      }
    }
    run += __popcll(m);
  }
}

// ---------------- pre-pass: permuted A panel in bf16 ----------------
__global__ __launch_bounds__(256) void perm_cast(
    const float* __restrict__ hidden, const int* __restrict__ tok_of_row,
    uint16_t* __restrict__ A1_perm) {
  const int srow = blockIdx.x;
  const int tok = tok_of_row[srow] & (TOKENS - 1);   // clamp vs poisoned ws
  const float* src = hidden + (size_t)tok * HIDDEN + threadIdx.x * 8;
  f32x4 a = *(const f32x4*)(src);
  f32x4 b = *(const f32x4*)(src + 4);
  uint4 v;
  v.x = pk2(a.x, a.y); v.y = pk2(a.z, a.w);
  v.z = pk2(b.x, b.y); v.w = pk2(b.z, b.w);
  *(uint4*)(A1_perm + (size_t)srow * HIDDEN + threadIdx.x * 8) = v;
}

// ---------------- GEMM1: h = A1 * W1^T, silu(gate)*up -> A_ws (bf16) ----------------
// BM=128, BN=256 (128 gate + 128 up, paired per wave), BK=32, 512 thr = 8 waves (2M x 4N).
// Both operands via global_load_lds; LDS 80KB dbuf -> 2 blocks/CU; <=128 VGPR forced.
__global__ __launch_bounds__(512, 4) void moe_gemm1(
    const uint16_t* __restrict__ A1_perm, const float* __restrict__ w1,
    const int* __restrict__ offs, uint16_t* __restrict__ A_ws)
{
  const int s = blockIdx.x;            // 1408 = 176*8
  const int xcd = s & 7, kk = s >> 3;  // kk: 0..175
  const int mt = kk & 3, pl = kk >> 2; // 4 mt of same (e,ns) adjacent on one XCD (B L2 reuse)
  const int pair = pl * 8 + xcd;       // 0..351
  const int e = pair / 11, ns = pair % 11;

  const int off = offs[e];
  const int cnt = min(offs[e + 1] - off, CAP);
  if (mt * 128 >= cnt) return;

  __shared__ __align__(16) char lds[81920];  // A 2x8KB @0 ; B(fp32) 2x32KB @16384
  const int tid = threadIdx.x;

  // A staging: LDS row r = tid>>2 (64B bf16 rows), slot ss=(tid&3)^((r>>1)&3)
  const uint16_t* asrc;
  {
    int r = tid >> 2;
    int srow = min(off + mt * 128 + r, TA - 1);    // dead rows guarded at epilogue
    int ss = (tid & 3) ^ ((r >> 1) & 3);
    asrc = A1_perm + (size_t)srow * HIDDEN + ss * 8;
  }
  // B staging: LDS row r = j*64 + tid>>3 (128B fp32 rows), slot s8=(tid&7)^(r&7)
  // col(r): q=(r>>5)&1 gate/up, wn=r>>6, i=r&31 -> q*HALFI + ns*128 + wn*32 + i
  const float* bsrc[4];
#pragma unroll
  for (int j = 0; j < 4; ++j) {
    int r = j * 64 + (tid >> 3);
    int q = (r >> 5) & 1, wnc = r >> 6, i = r & 31;
    int col = q * HALFI + ns * 128 + wnc * 32 + i;
    int s8 = (tid & 7) ^ (r & 7);
    bsrc[j] = w1 + ((size_t)e * INTER + col) * HIDDEN + s8 * 4;
  }
  const u32 dst16 = (u32)tid * 16;

  auto STAGE = [&](int buf, int k0) {
    char* ab = lds + buf * 8192;
    char* bb = lds + 16384 + buf * 32768;
#pragma unroll
    for (int j = 0; j < 4; ++j) gload16(bsrc[j] + k0, bb + j * 8192 + dst16);
    gload16(asrc + k0, ab + dst16);
  };

  const int lane = tid & 63, wv = tid >> 6;
  const int wm = (wv >> 2) * 64;       // M half (64 rows)
  const int wn = wv & 3;               // N quarter (64 B-rows = 32 gate + 32 up)
  const int fr = lane & 15, fq = lane >> 4;

  f32x4 acc[4][4];
#pragma unroll
  for (int i = 0; i < 4; ++i)
#pragma unroll
    for (int j = 0; j < 4; ++j) acc[i][j] = (f32x4)0.f;

  u32 aoffr[4], bofflo[4], boffhi[4];
#pragma unroll
  for (int mf = 0; mf < 4; ++mf) {
    int r = wm + mf * 16 + fr;
    aoffr[mf] = (u32)(r * 64 + ((fq ^ ((r >> 1) & 3)) * 16));
  }
#pragma unroll
  for (int nf = 0; nf < 4; ++nf) {
    int r = wn * 64 + nf * 16 + fr;
    bofflo[nf] = (u32)(r * 128 + (((2 * fq) ^ (r & 7)) * 16));
    boffhi[nf] = (u32)(r * 128 + (((2 * fq + 1) ^ (r & 7)) * 16));
  }

  const int NT = HIDDEN / BK;  // 64
  STAGE(0, 0);
  int cur = 0;
  for (int t = 0; t < NT; ++t) {
    __syncthreads();                         // drains gloads -> buf[cur] ready
    if (t + 1 < NT) STAGE(cur ^ 1, (t + 1) * BK);
    const char* ab = lds + cur * 8192;
    const char* bb = lds + 16384 + cur * 32768;
    bf16x8 af[4];
#pragma unroll
    for (int mf = 0; mf < 4; ++mf) af[mf] = *(const bf16x8*)(ab + aoffr[mf]);
#pragma unroll
    for (int nf = 0; nf < 4; ++nf) {
      f32x4 lo = *(const f32x4*)(bb + bofflo[nf]);
      f32x4 hi = *(const f32x4*)(bb + boffhi[nf]);
      bf16x8 bv = cvt8(lo, hi);
#pragma unroll
      for (int mf = 0; mf < 4; ++mf)
        acc[mf][nf] = __builtin_amdgcn_mfma_f32_16x16x32_bf16(af[mf], bv, acc[mf][nf], 0, 0, 0);
    }
    cur ^= 1;
  }

  // epilogue: gate (nf 0,1) pairs with up (nf 2,3), same output col
#pragma unroll
  for (int mf = 0; mf < 4; ++mf) {
#pragma unroll
    for (int r = 0; r < 4; ++r) {
      int grow = mt * 128 + wm + mf * 16 + fq * 4 + r;
      if (grow < cnt) {
        size_t srow = (size_t)(off + grow);
#pragma unroll
        for (int nf = 0; nf < 2; ++nf) {
          float g = acc[mf][nf][r];
          float u = acc[mf][nf + 2][r];
          float val = g / (1.f + __expf(-g)) * u;
          A_ws[srow * HALFI + ns * 128 + wn * 32 + nf * 16 + fr] = bf16b(val);
        }
      }
    }
  }
}

// ---------------- GEMM2: out += (A_ws * W2^T) * w, atomic scatter-add ----------------
// BM=128, BN=256, BK=32, 512 thr (2M x 4N waves), same staging machinery.
__global__ __launch_bounds__(512, 4) void moe_gemm2(
    const uint16_t* __restrict__ A_ws, const float* __restrict__ w2,
    const int* __restrict__ offs, const int* __restrict__ tok_of_row,
    const float* __restrict__ w_of_row, float* __restrict__ out)
{
  const int s = blockIdx.x;            // 1024 = 128*8
  const int xcd = s & 7, kk = s >> 3;  // kk: 0..127
  const int mt = kk & 3, pl = kk >> 2; // pl: 0..31
  const int pair = pl * 8 + xcd;       // 0..255
  const int e = pair >> 3, ns = pair & 7;

  const int off = offs[e];
  const int cnt = min(offs[e + 1] - off, CAP);
  if (mt * 128 >= cnt) return;

  __shared__ __align__(16) char lds[81920];
  const int tid = threadIdx.x;

  const uint16_t* asrc;
  {
    int r = tid >> 2;
    int srow = min(off + mt * 128 + r, TA - 1);
    int ss = (tid & 3) ^ ((r >> 1) & 3);
    asrc = A_ws + (size_t)srow * HALFI + ss * 8;
  }
  const float* bsrc[4];
#pragma unroll
  for (int j = 0; j < 4; ++j) {
    int r = j * 64 + (tid >> 3);
    int col = ns * 256 + r;
    int s8 = (tid & 7) ^ (r & 7);
    bsrc[j] = w2 + ((size_t)e * HIDDEN + col) * HALFI + s8 * 4;
  }
  const u32 dst16 = (u32)tid * 16;

  auto STAGE = [&](int buf, int k0) {
    char* ab = lds + buf * 8192;
    char* bb = lds + 16384 + buf * 32768;
#pragma unroll
    for (int j = 0; j < 4; ++j) gload16(bsrc[j] + k0, bb + j * 8192 + dst16);
    gload16(asrc + k0, ab + dst16);
  };

  const int lane = tid & 63, wv = tid >> 6;
  const int wm = (wv >> 2) * 64;
  const int wn = wv & 3;
  const int fr = lane & 15, fq = lane >> 4;

  f32x4 acc[4][4];
#pragma unroll
  for (int i = 0; i < 4; ++i)
#pragma unroll
    for (int j = 0; j < 4; ++j) acc[i][j] = (f32x4)0.f;

  u32 aoffr[4], bofflo[4], boffhi[4];
#pragma unroll
  for (int mf = 0; mf < 4; ++mf) {
    int r = wm + mf * 16 + fr;
    aoffr[mf] = (u32)(r * 64 + ((fq ^ ((r >> 1) & 3)) * 16));
  }
#pragma unroll
  for (int nf = 0; nf < 4; ++nf) {
    int r = wn * 64 + nf * 16 + fr;
    bofflo[nf] = (u32)(r * 128 + (((2 * fq) ^ (r & 7)) * 16));
    boffhi[nf] = (u32)(r * 128 + (((2 * fq + 1) ^ (r & 7)) * 16));
  }

  const int NT = HALFI / BK;  // 44
  STAGE(0, 0);
  int cur = 0;
  for (int t = 0; t < NT; ++t) {
    __syncthreads();
    if (t + 1 < NT) STAGE(cur ^ 1, (t + 1) * BK);
    const char* ab = lds + cur * 8192;
    const char* bb = lds + 16384 + cur * 32768;
    bf16x8 af[4];
#pragma unroll
    for (int mf = 0; mf < 4; ++mf) af[mf] = *(const bf16x8*)(ab + aoffr[mf]);
#pragma unroll
    for (int nf = 0; nf < 4; ++nf) {
      f32x4 lo = *(const f32x4*)(bb + bofflo[nf]);
      f32x4 hi = *(const f32x4*)(bb + boffhi[nf]);
      bf16x8 bv = cvt8(lo, hi);
#pragma unroll
      for (int mf = 0; mf < 4; ++mf)
        acc[mf][nf] = __builtin_amdgcn_mfma_f32_16x16x32_bf16(af[mf], bv, acc[mf][nf], 0, 0, 0);
    }
    cur ^= 1;
  }

  // epilogue: weighted atomic scatter-add into token rows
#pragma unroll
  for (int mf = 0; mf < 4; ++mf) {
#pragma unroll
    for (int r = 0; r < 4; ++r) {
      int grow = mt * 128 + wm + mf * 16 + fq * 4 + r;
      if (grow < cnt) {
        int srow = off + grow;
        int tokn = tok_of_row[srow];
        float wgt = w_of_row[srow];
        float* po = out + (size_t)tokn * HIDDEN + ns * 256 + wn * 64 + fr;
#pragma unroll
        for (int nf = 0; nf < 4; ++nf)
          atomicAdd(po + nf * 16, acc[mf][nf][r] * wgt);
      }
    }
  }
}

extern "C" void kernel_launch(void* const* d_in, const int* in_sizes, int n_in,
                              void* d_out, int out_size, void* d_ws, size_t ws_size,
                              hipStream_t stream) {
  const float* hidden = (const float*)d_in[0];
  const float* topk_w = (const float*)d_in[1];
  const float* w1     = (const float*)d_in[2];
  const float* w2     = (const float*)d_in[3];
  const int*   tkidx  = (const int*)d_in[4];

  char* ws = (char*)d_ws;
  int*      offs       = (int*)ws;                          // 33 ints
  int*      tok_of_row = (int*)(ws + 1024);                 // TA ints
  float*    w_of_row   = (float*)(ws + 1024 + 4 * TA);      // TA floats
  uint16_t* A1_perm    = (uint16_t*)(ws + 131072);          // TA x 2048 bf16 (33.5 MB)
  uint16_t* A_ws       = (uint16_t*)(ws + 131072 + (size_t)TA * HIDDEN * 2);  // TA x 1408 bf16
  float*    out        = (float*)d_out;

  hipMemsetAsync(d_out, 0, (size_t)out_size * sizeof(float), stream);
  route_count<<<1, 256, 0, stream>>>(tkidx, offs);
  route_build<<<NUM_EXPERTS, 64, 0, stream>>>(tkidx, topk_w, offs, tok_of_row, w_of_row);
  perm_cast<<<TA, 256, 0, stream>>>(hidden, tok_of_row, A1_perm);
  moe_gemm1<<<dim3(11 * 32 * 4), 512, 0, stream>>>(A1_perm, w1, offs, A_ws);
  moe_gemm2<<<dim3(8 * 32 * 4), 512, 0, stream>>>(A_ws, w2, offs, tok_of_row, w_of_row, out);
}